// Round 2
// baseline (296.539 us; speedup 1.0000x reference)
//
#include <hip/hip_runtime.h>
#include <hip/hip_bf16.h>

// Shapes fixed by the reference: B=32, T=1024, F=4096, D=384.
#define B_ 32
#define T_ 1024
#define F_ 4096
#define D_ 384
#define D4_ 96   // D/4 float4 per row

// Native clang vector type — required by __builtin_nontemporal_store.
typedef float vfloat4 __attribute__((ext_vector_type(4)));

// Kernel 1: per-batch run-count prefix sum.
// idx[b][j] = idx[b][j-1] + (align[b][j] != align[b][j-1]), idx[b][0] = 0.
// Equivalent to the reference's sequential pointer walk because align is
// repeat(text, dur) with adjacent text phones guaranteed distinct, so the
// walker's `before` always equals align[j] after step j. text_phone unused.
__global__ __launch_bounds__(256) void scan_idx_kernel(
    const int* __restrict__ align, int* __restrict__ idx)
{
    const int b = blockIdx.x;
    const int t = threadIdx.x;
    const int CHUNK = F_ / 256;  // 16
    const int* a = align + (size_t)b * F_;
    int*       o = idx   + (size_t)b * F_;
    const int start = t * CHUNK;

    int vals[CHUNK];
#pragma unroll
    for (int i = 0; i < CHUNK; ++i) vals[i] = a[start + i];

    // prev = element before this chunk; for thread 0 use vals[0] so the
    // first comparison yields "no change" -> idx[0] = 0.
    int prev = (start == 0) ? vals[0] : a[start - 1];

    int loc[CHUNK];
    int cnt = 0;
#pragma unroll
    for (int i = 0; i < CHUNK; ++i) {
        cnt += (vals[i] != prev) ? 1 : 0;
        loc[i] = cnt;
        prev = vals[i];
    }

    // Exclusive scan of per-thread counts across the block (Hillis-Steele).
    __shared__ int s[256];
    s[t] = cnt;
    __syncthreads();
    for (int off = 1; off < 256; off <<= 1) {
        int v = (t >= off) ? s[t - off] : 0;
        __syncthreads();
        s[t] += v;
        __syncthreads();
    }
    const int base = s[t] - cnt;  // exclusive prefix

#pragma unroll
    for (int i = 0; i < CHUNK; ++i) o[start + i] = base + loc[i];
}

// Kernel 2: out[b,f,d] = enc[b, idx[b,f], d]
//                      + pitch[b,f]*w_pitch[d] + b_pitch[d]
//                      + beats[b,f]*w_beats[d] + b_beats[d]
//                      + f*w_pos[d] + b_pos[d]
// One float4 per thread; 96 float4 per (b,f) row. Exact grid, no bounds check.
__global__ __launch_bounds__(256) void postnet_kernel(
    const vfloat4* __restrict__ enc,    // [B*T*96]
    const int*     __restrict__ idx,    // [B*F]
    const float*   __restrict__ pitch,  // [B*F]
    const float*   __restrict__ beats,  // [B*F]
    const vfloat4* __restrict__ wp, const vfloat4* __restrict__ bp,
    const vfloat4* __restrict__ wb, const vfloat4* __restrict__ bb,
    const vfloat4* __restrict__ wq, const vfloat4* __restrict__ bq,
    vfloat4* __restrict__ out)          // [B*F*96]
{
    const int g  = blockIdx.x * 256 + threadIdx.x;  // < B*F*96 = 12,582,912
    const int d4 = g % D4_;
    const int rf = g / D4_;            // row id in [0, B*F)
    const int f  = rf & (F_ - 1);
    const int b  = rf >> 12;           // F = 4096 = 2^12

    const int   e  = idx[rf];
    const float pv = pitch[rf];
    const float bv = beats[rf];
    const float fv = (float)f;

    const vfloat4 ev = enc[(size_t)(b * T_ + e) * D4_ + d4];
    const vfloat4 w1 = wp[d4], o1 = bp[d4];
    const vfloat4 w2 = wb[d4], o2 = bb[d4];
    const vfloat4 w3 = wq[d4], o3 = bq[d4];

    vfloat4 r = ev + (pv * w1 + o1) + (bv * w2 + o2) + (fv * w3 + o3);

    // Streaming output, never re-read: nontemporal store keeps L2 for the
    // encoder-row gather reuse.
    __builtin_nontemporal_store(r, &out[g]);
}

extern "C" void kernel_launch(void* const* d_in, const int* in_sizes, int n_in,
                              void* d_out, int out_size, void* d_ws, size_t ws_size,
                              hipStream_t stream) {
    const float* enc     = (const float*)d_in[0];   // [B,T,D] f32
    const int*   align   = (const int*)  d_in[1];   // [B,F]
    // d_in[2] = text_phone — unused (see scan_idx_kernel comment)
    const float* pitch   = (const float*)d_in[3];   // [B,F]
    const float* beats   = (const float*)d_in[4];   // [B,F]
    const float* w_pitch = (const float*)d_in[5];
    const float* b_pitch = (const float*)d_in[6];
    const float* w_beats = (const float*)d_in[7];
    const float* b_beats = (const float*)d_in[8];
    const float* w_pos   = (const float*)d_in[9];
    const float* b_pos   = (const float*)d_in[10];

    int* idx_ws = (int*)d_ws;  // B*F ints = 512 KB

    scan_idx_kernel<<<B_, 256, 0, stream>>>(align, idx_ws);

    const int total4 = B_ * F_ * D4_;         // 12,582,912
    const int blocks = total4 / 256;          // 49,152 exact
    postnet_kernel<<<blocks, 256, 0, stream>>>(
        (const vfloat4*)enc, idx_ws, pitch, beats,
        (const vfloat4*)w_pitch, (const vfloat4*)b_pitch,
        (const vfloat4*)w_beats, (const vfloat4*)b_beats,
        (const vfloat4*)w_pos,   (const vfloat4*)b_pos,
        (vfloat4*)d_out);
}

// Round 3
// 267.685 us; speedup vs baseline: 1.1078x; 1.1078x over previous
//
#include <hip/hip_runtime.h>
#include <hip/hip_bf16.h>

// Shapes fixed by the reference: B=32, T=1024, F=4096, D=384.
#define B_ 32
#define T_ 1024
#define F_ 4096
#define D_ 384
#define D4_ 96   // D/4 float4 per row

// Native clang vector types — required by __builtin_nontemporal_store.
typedef float vfloat4 __attribute__((ext_vector_type(4)));
typedef int   vint4   __attribute__((ext_vector_type(4)));

// Kernel 1: per-batch run-count prefix sum.
// idx[b][j] = idx[b][j-1] + (align[b][j] != align[b][j-1]), idx[b][0] = 0.
// Equivalent to the reference's sequential pointer walk because align is
// repeat(text, dur) with adjacent text phones guaranteed distinct, so the
// walker's `before` always equals align[j] after step j. text_phone unused.
__global__ __launch_bounds__(256) void scan_idx_kernel(
    const int* __restrict__ align, int* __restrict__ idx)
{
    const int b = blockIdx.x;
    const int t = threadIdx.x;
    const int CHUNK = F_ / 256;  // 16
    const int* a = align + (size_t)b * F_;
    int*       o = idx   + (size_t)b * F_;
    const int start = t * CHUNK;

    int vals[CHUNK];
#pragma unroll
    for (int i = 0; i < CHUNK; ++i) vals[i] = a[start + i];

    int prev = (start == 0) ? vals[0] : a[start - 1];

    int loc[CHUNK];
    int cnt = 0;
#pragma unroll
    for (int i = 0; i < CHUNK; ++i) {
        cnt += (vals[i] != prev) ? 1 : 0;
        loc[i] = cnt;
        prev = vals[i];
    }

    __shared__ int s[256];
    s[t] = cnt;
    __syncthreads();
    for (int off = 1; off < 256; off <<= 1) {
        int v = (t >= off) ? s[t - off] : 0;
        __syncthreads();
        s[t] += v;
        __syncthreads();
    }
    const int base = s[t] - cnt;  // exclusive prefix

#pragma unroll
    for (int i = 0; i < CHUNK; ++i) o[start + i] = base + loc[i];
}

// Kernel 2 (ILP-4): each thread handles 4 consecutive frames (one row-group)
// at a fixed d4. idx/pitch/beats for the 4 rows come in as one vector load
// each (broadcast across the 96 threads of the row-group); the 4 enc gathers
// are independent chains; weight loads amortize over 4 outputs.
__global__ __launch_bounds__(256) void postnet_kernel(
    const vfloat4* __restrict__ enc,     // [B*T*96]
    const vint4*   __restrict__ idx4,    // [B*F/4]
    const vfloat4* __restrict__ pitch4,  // [B*F/4]
    const vfloat4* __restrict__ beats4,  // [B*F/4]
    const vfloat4* __restrict__ wp, const vfloat4* __restrict__ bp,
    const vfloat4* __restrict__ wb, const vfloat4* __restrict__ bb,
    const vfloat4* __restrict__ wq, const vfloat4* __restrict__ bq,
    vfloat4* __restrict__ out)           // [B*F*96]
{
    const int g   = blockIdx.x * 256 + threadIdx.x;  // < (B*F/4)*96 = 3,145,728
    const int d4  = g % D4_;
    const int rg  = g / D4_;            // row-group id in [0, B*F/4)
    const int rf0 = rg * 4;             // first frame of the group
    const int f0  = rf0 & (F_ - 1);
    const int b   = rf0 >> 12;          // F = 4096 = 2^12

    const vint4   e4 = idx4[rg];
    const vfloat4 pv = pitch4[rg];
    const vfloat4 bv = beats4[rg];

    const vfloat4 w1 = wp[d4], w2 = wb[d4], w3 = wq[d4];
    const vfloat4 osum = bp[d4] + bb[d4] + bq[d4];

    const vfloat4* encb = enc + (size_t)b * T_ * D4_ + d4;
    const vfloat4 ev0 = encb[(size_t)e4.x * D4_];
    const vfloat4 ev1 = encb[(size_t)e4.y * D4_];
    const vfloat4 ev2 = encb[(size_t)e4.z * D4_];
    const vfloat4 ev3 = encb[(size_t)e4.w * D4_];

    const float fv = (float)f0;
    vfloat4 r0 = ev0 + pv.x * w1 + bv.x * w2 + (fv + 0.f) * w3 + osum;
    vfloat4 r1 = ev1 + pv.y * w1 + bv.y * w2 + (fv + 1.f) * w3 + osum;
    vfloat4 r2 = ev2 + pv.z * w1 + bv.z * w2 + (fv + 2.f) * w3 + osum;
    vfloat4 r3 = ev3 + pv.w * w1 + bv.w * w2 + (fv + 3.f) * w3 + osum;

    vfloat4* o = out + (size_t)rf0 * D4_ + d4;
    __builtin_nontemporal_store(r0, o + 0 * D4_);
    __builtin_nontemporal_store(r1, o + 1 * D4_);
    __builtin_nontemporal_store(r2, o + 2 * D4_);
    __builtin_nontemporal_store(r3, o + 3 * D4_);
}

extern "C" void kernel_launch(void* const* d_in, const int* in_sizes, int n_in,
                              void* d_out, int out_size, void* d_ws, size_t ws_size,
                              hipStream_t stream) {
    const float* enc     = (const float*)d_in[0];   // [B,T,D] f32
    const int*   align   = (const int*)  d_in[1];   // [B,F]
    // d_in[2] = text_phone — unused (see scan_idx_kernel comment)
    const float* pitch   = (const float*)d_in[3];   // [B,F]
    const float* beats   = (const float*)d_in[4];   // [B,F]
    const float* w_pitch = (const float*)d_in[5];
    const float* b_pitch = (const float*)d_in[6];
    const float* w_beats = (const float*)d_in[7];
    const float* b_beats = (const float*)d_in[8];
    const float* w_pos   = (const float*)d_in[9];
    const float* b_pos   = (const float*)d_in[10];

    int* idx_ws = (int*)d_ws;  // B*F ints = 512 KB, 16B-aligned (ws base)

    scan_idx_kernel<<<B_, 256, 0, stream>>>(align, idx_ws);

    const int total = (B_ * F_ / 4) * D4_;    // 3,145,728 threads
    const int blocks = total / 256;           // 12,288 exact
    postnet_kernel<<<blocks, 256, 0, stream>>>(
        (const vfloat4*)enc, (const vint4*)idx_ws,
        (const vfloat4*)pitch, (const vfloat4*)beats,
        (const vfloat4*)w_pitch, (const vfloat4*)b_pitch,
        (const vfloat4*)w_beats, (const vfloat4*)b_beats,
        (const vfloat4*)w_pos,   (const vfloat4*)b_pos,
        (vfloat4*)d_out);
}